// Round 1
// baseline (773.026 us; speedup 1.0000x reference)
//
#include <hip/hip_runtime.h>

#define NROWS 8192
#define FIN 1024
#define FOUT 512

typedef __attribute__((ext_vector_type(8))) short short8;
typedef __attribute__((ext_vector_type(4))) float f32x4;
typedef __attribute__((ext_vector_type(4))) unsigned short us4;

static __device__ __forceinline__ unsigned short f2bf(float f) {
  unsigned int u = __float_as_uint(f);
  u += 0x7fffu + ((u >> 16) & 1u);
  return (unsigned short)(u >> 16);
}
static __device__ __forceinline__ float bf2f(unsigned short h) {
  return __uint_as_float(((unsigned int)h) << 16);
}
static __device__ __forceinline__ void load_lds16(const void* g, void* l) {
  __builtin_amdgcn_global_load_lds((const __attribute__((address_space(1))) void*)g,
                                   (__attribute__((address_space(3))) void*)l, 16, 0, 0);
}

// ---------------- split-cast: fp32 -> (bf16 hi, bf16 lo residual) -------------
__global__ void k_split(const float* __restrict__ x, const float* __restrict__ w,
                        unsigned short* __restrict__ hi, unsigned short* __restrict__ lo) {
  long long base = ((long long)blockIdx.x * blockDim.x + threadIdx.x) * 4;
  const long long NX = (long long)NROWS * FIN;
  const float* src = (base < NX) ? (x + base) : (w + (base - NX));
  float4 v = *(const float4*)src;
  unsigned short h0 = f2bf(v.x), h1 = f2bf(v.y), h2 = f2bf(v.z), h3 = f2bf(v.w);
  us4 hv = {h0, h1, h2, h3};
  us4 lv = {f2bf(v.x - bf2f(h0)), f2bf(v.y - bf2f(h1)),
            f2bf(v.z - bf2f(h2)), f2bf(v.w - bf2f(h3))};
  *(us4*)(hi + base) = hv;
  *(us4*)(lo + base) = lv;
}

// ---------------- GEMM1: seq_fts = x @ seq_W^T, split-bf16 (3 MFMA terms) -----
__global__ __launch_bounds__(256) void k_gemm1(const unsigned short* __restrict__ ah,
                                               const unsigned short* __restrict__ al,
                                               float* __restrict__ c) {
  __shared__ unsigned short sAh[128 * 32], sAl[128 * 32], sBh[64 * 32], sBl[64 * 32];
  const int tid = threadIdx.x;
  const int w = tid >> 6, l = tid & 63;
  const int bm = blockIdx.x >> 3, bn = blockIdx.x & 7;
  const int i0 = bm * 128, n0 = bn * 64;
  const unsigned short* bhp = ah + (long long)NROWS * FIN;
  const unsigned short* blp = al + (long long)NROWS * FIN;
  const int m_off = (w & 1) * 64, n_off = (w >> 1) * 32;
  const int lrow = l >> 2, lch = (l & 3) * 8;
  f32x4 acc[4][2] = {};
  for (int k0 = 0; k0 < FIN; k0 += 32) {
    __syncthreads();
    {
      int rA0 = w * 32, rA1 = w * 32 + 16, rB = w * 16;
      long long ga0 = (long long)(i0 + rA0 + lrow) * FIN + k0 + lch;
      long long ga1 = (long long)(i0 + rA1 + lrow) * FIN + k0 + lch;
      long long gb = (long long)(n0 + rB + lrow) * FIN + k0 + lch;
      load_lds16(ah + ga0, &sAh[rA0 * 32]);
      load_lds16(ah + ga1, &sAh[rA1 * 32]);
      load_lds16(al + ga0, &sAl[rA0 * 32]);
      load_lds16(al + ga1, &sAl[rA1 * 32]);
      load_lds16(bhp + gb, &sBh[rB * 32]);
      load_lds16(blp + gb, &sBl[rB * 32]);
    }
    __syncthreads();
    short8 a_h[4], a_l[4], b_h[2], b_l[2];
#pragma unroll
    for (int mi = 0; mi < 4; ++mi) {
      int off = (m_off + mi * 16 + (l & 15)) * 32 + (l >> 4) * 8;
      a_h[mi] = *(const short8*)&sAh[off];
      a_l[mi] = *(const short8*)&sAl[off];
    }
#pragma unroll
    for (int ni = 0; ni < 2; ++ni) {
      int off = (n_off + ni * 16 + (l & 15)) * 32 + (l >> 4) * 8;
      b_h[ni] = *(const short8*)&sBh[off];
      b_l[ni] = *(const short8*)&sBl[off];
    }
#pragma unroll
    for (int mi = 0; mi < 4; ++mi)
#pragma unroll
      for (int ni = 0; ni < 2; ++ni) {
        acc[mi][ni] = __builtin_amdgcn_mfma_f32_16x16x32_bf16(a_h[mi], b_h[ni], acc[mi][ni], 0, 0, 0);
        acc[mi][ni] = __builtin_amdgcn_mfma_f32_16x16x32_bf16(a_h[mi], b_l[ni], acc[mi][ni], 0, 0, 0);
        acc[mi][ni] = __builtin_amdgcn_mfma_f32_16x16x32_bf16(a_l[mi], b_h[ni], acc[mi][ni], 0, 0, 0);
      }
  }
#pragma unroll
  for (int mi = 0; mi < 4; ++mi)
#pragma unroll
    for (int ni = 0; ni < 2; ++ni)
#pragma unroll
      for (int rg = 0; rg < 4; ++rg) {
        int row = i0 + m_off + mi * 16 + (l >> 4) * 4 + rg;
        int col = n0 + n_off + ni * 16 + (l & 15);
        c[(long long)row * FOUT + col] = acc[mi][ni][rg];
      }
}

// ---------------- f1/f2: per-row dots of seq_fts with f1_w / f2_w ------------
__global__ void k_f1f2(const float* __restrict__ sf, const float* __restrict__ f1w,
                       const float* __restrict__ f1b, const float* __restrict__ f2w,
                       const float* __restrict__ f2b, float* __restrict__ f1,
                       float* __restrict__ f2) {
  int w = threadIdx.x >> 6, l = threadIdx.x & 63;
  int i = blockIdx.x * 4 + w;
  const float* row = sf + (long long)i * FOUT;
  float4 v0 = *(const float4*)(row + l * 8);
  float4 v1 = *(const float4*)(row + l * 8 + 4);
  float4 a0 = *(const float4*)(f1w + l * 8);
  float4 a1 = *(const float4*)(f1w + l * 8 + 4);
  float4 b0 = *(const float4*)(f2w + l * 8);
  float4 b1 = *(const float4*)(f2w + l * 8 + 4);
  float s1 = v0.x * a0.x + v0.y * a0.y + v0.z * a0.z + v0.w * a0.w +
             v1.x * a1.x + v1.y * a1.y + v1.z * a1.z + v1.w * a1.w;
  float s2 = v0.x * b0.x + v0.y * b0.y + v0.z * b0.z + v0.w * b0.w +
             v1.x * b1.x + v1.y * b1.y + v1.z * b1.z + v1.w * b1.w;
#pragma unroll
  for (int m = 1; m < 64; m <<= 1) {
    s1 += __shfl_xor(s1, m, 64);
    s2 += __shfl_xor(s2, m, 64);
  }
  if (l == 0) {
    f1[i] = s1 + f1b[0];
    f2[i] = s2 + f2b[0];
  }
}

// ---------------- pack: V into MFMA-B-fragment order ------------------------
// vtp[((kt*32 + nt)*64 + lane)*8 + j] = bf16(sf[kt*32 + (lane>>4)*8 + j][nt*16 + (lane&15)])
__global__ __launch_bounds__(256) void k_pack(const float* __restrict__ sf,
                                              unsigned short* __restrict__ vtp) {
  __shared__ unsigned short tile[32][33];
  const int t = threadIdx.x;
  const int k0 = blockIdx.x * 32;   // NROWS/32 = 256
  const int n0 = blockIdx.y * 32;   // FOUT/32 = 16
  {
    int kk = t >> 3, nq = (t & 7) * 4;
    float4 v = *(const float4*)(sf + (long long)(k0 + kk) * FOUT + n0 + nq);
    tile[kk][nq] = f2bf(v.x);
    tile[kk][nq + 1] = f2bf(v.y);
    tile[kk][nq + 2] = f2bf(v.z);
    tile[kk][nq + 3] = f2bf(v.w);
  }
  __syncthreads();
  int nt_loc = t >> 7, tt = t & 127;
  int lane = tt >> 1, jh = (tt & 1) * 4;
  int n_loc = nt_loc * 16 + (lane & 15);
  int k_loc = (lane >> 4) * 8 + jh;
  us4 u = {tile[k_loc][n_loc], tile[k_loc + 1][n_loc], tile[k_loc + 2][n_loc],
           tile[k_loc + 3][n_loc]};
  long long kt = blockIdx.x;
  long long nt = (long long)blockIdx.y * 2 + nt_loc;
  *(us4*)(vtp + ((kt * 32 + nt) * 64 + lane) * 8 + jh) = u;
}

// ---------------- flash attention partials (split-j 2-way) -------------------
// 512 blocks x 512 threads; 32 Q-rows/block; each block covers 4096 j-cols
// (32 tiles of 128). Raw s_barrier with lgkmcnt-only drain keeps the adj/f2
// prefetch in flight across the barrier (no vmcnt(0) drain). Always-rescale
// (alpha==1 when max unchanged) removes the need for __syncthreads_or.
// Partition swizzle: XCDs 0-3 get part 0, XCDs 4-7 part 1 -> each partition's
// 4 MB half of vtp fits one XCD L2.
__global__ __launch_bounds__(512) void k_flashp(const float* __restrict__ adj,
                                                const float* __restrict__ f1,
                                                const float* __restrict__ f2,
                                                const unsigned short* __restrict__ vtp,
                                                float* __restrict__ pacc,
                                                float* __restrict__ pstats) {
  __shared__ short p_sh[2][2][4][64][8];  // [buf][mi][ks][lane][8] = 16 KB
  __shared__ float alpha_sh[2][32];
  const int tid = threadIdx.x, l = tid & 63, w = tid >> 6;
  const int rloc = tid >> 4, c16 = tid & 15;
  // blockIdx -> (part, rb): bit2 selects partition (XCD round-robin mod 8)
  const int part = (blockIdx.x >> 2) & 1;
  const int rb = ((blockIdx.x >> 3) << 2) | (blockIdx.x & 3);
  const int r0 = rb * 32;
  const int jbase = part * 4096;
  const long long arow = (long long)(r0 + rloc) * NROWS;
  const float f1r = f1[r0 + rloc];
  const int nt_base = w * 4;  // 4 n-tiles of 16 per wave -> 64 cols
  const int mi_p = rloc >> 4;
  const int ks_p = c16 >> 2;
  const int lp = (rloc & 15) | ((c16 & 3) << 4);
  float m = -3.0e38f, lsum = 0.f;
  f32x4 acc[2][4] = {};
  float4 a0 = *(const float4*)(adj + arow + jbase + c16 * 8);
  float4 a1 = *(const float4*)(adj + arow + jbase + c16 * 8 + 4);
  float4 f20 = *(const float4*)(f2 + jbase + c16 * 8);
  float4 f21 = *(const float4*)(f2 + jbase + c16 * 8 + 4);
  for (int t = 0; t < 32; ++t) {
    const int j0 = jbase + t * 128;
    const int buf = t & 1;
    float z, p0, p1, p2, p3, p4, p5, p6, p7;
    z = f1r + f20.x; p0 = (z > 0.f ? z : 0.2f * z) + a0.x;
    z = f1r + f20.y; p1 = (z > 0.f ? z : 0.2f * z) + a0.y;
    z = f1r + f20.z; p2 = (z > 0.f ? z : 0.2f * z) + a0.z;
    z = f1r + f20.w; p3 = (z > 0.f ? z : 0.2f * z) + a0.w;
    z = f1r + f21.x; p4 = (z > 0.f ? z : 0.2f * z) + a1.x;
    z = f1r + f21.y; p5 = (z > 0.f ? z : 0.2f * z) + a1.y;
    z = f1r + f21.z; p6 = (z > 0.f ? z : 0.2f * z) + a1.z;
    z = f1r + f21.w; p7 = (z > 0.f ? z : 0.2f * z) + a1.w;
    float mt = fmaxf(fmaxf(fmaxf(p0, p1), fmaxf(p2, p3)), fmaxf(fmaxf(p4, p5), fmaxf(p6, p7)));
    mt = fmaxf(mt, __shfl_xor(mt, 1, 64));
    mt = fmaxf(mt, __shfl_xor(mt, 2, 64));
    mt = fmaxf(mt, __shfl_xor(mt, 4, 64));
    mt = fmaxf(mt, __shfl_xor(mt, 8, 64));
    float m_new = fmaxf(m, mt);
    float al = __expf(m - m_new);  // == 1.0 when max unchanged
    p0 = __expf(p0 - m_new); p1 = __expf(p1 - m_new);
    p2 = __expf(p2 - m_new); p3 = __expf(p3 - m_new);
    p4 = __expf(p4 - m_new); p5 = __expf(p5 - m_new);
    p6 = __expf(p6 - m_new); p7 = __expf(p7 - m_new);
    float ps = p0 + p1 + p2 + p3 + p4 + p5 + p6 + p7;
    ps += __shfl_xor(ps, 1, 64);
    ps += __shfl_xor(ps, 2, 64);
    ps += __shfl_xor(ps, 4, 64);
    ps += __shfl_xor(ps, 8, 64);
    lsum = lsum * al + ps;
    m = m_new;
    if (c16 == 0) alpha_sh[buf][rloc] = al;
    short8 pv;
    pv[0] = (short)f2bf(p0); pv[1] = (short)f2bf(p1);
    pv[2] = (short)f2bf(p2); pv[3] = (short)f2bf(p3);
    pv[4] = (short)f2bf(p4); pv[5] = (short)f2bf(p5);
    pv[6] = (short)f2bf(p6); pv[7] = (short)f2bf(p7);
    *(short8*)&p_sh[buf][mi_p][ks_p][lp][0] = pv;
    // prefetch next tile's adj/f2 -- these stay in flight across the barrier
    const int jn = (t < 31) ? j0 + 128 : j0;
    float4 na0 = *(const float4*)(adj + arow + jn + c16 * 8);
    float4 na1 = *(const float4*)(adj + arow + jn + c16 * 8 + 4);
    float4 nf20 = *(const float4*)(f2 + jn + c16 * 8);
    float4 nf21 = *(const float4*)(f2 + jn + c16 * 8 + 4);
    // barrier with LDS-only drain: HBM prefetch NOT drained (unlike __syncthreads)
    asm volatile("s_waitcnt lgkmcnt(0)" ::: "memory");
    __builtin_amdgcn_s_barrier();
    asm volatile("" ::: "memory");
    // always-rescale (alpha broadcast-read from LDS; same-address = free)
    {
      f32x4 al0 = *(const f32x4*)&alpha_sh[buf][(l >> 4) * 4];
      f32x4 al1 = *(const f32x4*)&alpha_sh[buf][16 + (l >> 4) * 4];
#pragma unroll
      for (int ni = 0; ni < 4; ++ni)
#pragma unroll
        for (int rg = 0; rg < 4; ++rg) {
          acc[0][ni][rg] *= al0[rg];
          acc[1][ni][rg] *= al1[rg];
        }
    }
    const int kt0 = j0 >> 5;
    __builtin_amdgcn_s_setprio(1);
#pragma unroll
    for (int ks = 0; ks < 4; ++ks) {
      short8 af0 = *(const short8*)&p_sh[buf][0][ks][l][0];
      short8 af1 = *(const short8*)&p_sh[buf][1][ks][l][0];
      const unsigned short* bbase =
          vtp + (((long long)(kt0 + ks) * 32 + nt_base) * 64 + l) * 8;
#pragma unroll
      for (int ni = 0; ni < 4; ++ni) {
        short8 bf = *(const short8*)(bbase + ni * 512);
        acc[0][ni] = __builtin_amdgcn_mfma_f32_16x16x32_bf16(af0, bf, acc[0][ni], 0, 0, 0);
        acc[1][ni] = __builtin_amdgcn_mfma_f32_16x16x32_bf16(af1, bf, acc[1][ni], 0, 0, 0);
      }
    }
    __builtin_amdgcn_s_setprio(0);
    a0 = na0; a1 = na1; f20 = nf20; f21 = nf21;
  }
  // per-row stats (m, lsum replicated across the 16 lanes of a row group)
  if (c16 == 0) {
    pstats[part * 2 * NROWS + (r0 + rloc)] = m;
    pstats[part * 2 * NROWS + NROWS + (r0 + rloc)] = lsum;
  }
  // unnormalized partial accumulator
  float* pc = pacc + (long long)part * NROWS * FOUT;
#pragma unroll
  for (int mi = 0; mi < 2; ++mi)
#pragma unroll
    for (int rg = 0; rg < 4; ++rg) {
      int row = mi * 16 + (l >> 4) * 4 + rg;
      long long gr = (long long)(r0 + row) * FOUT;
#pragma unroll
      for (int ni = 0; ni < 4; ++ni) {
        int col = w * 64 + ni * 16 + (l & 15);
        pc[gr + col] = acc[mi][ni][rg];
      }
    }
}

// ---------------- combine the two j-partitions + bias + elu ------------------
__global__ __launch_bounds__(512) void k_combine(const float* __restrict__ pacc,
                                                 const float* __restrict__ pstats,
                                                 const float* __restrict__ bias,
                                                 float* __restrict__ out) {
  const int tid = threadIdx.x;
  const int row = blockIdx.x * 4 + (tid >> 7);
  const int col = (tid & 127) * 4;
  const float m0 = pstats[row], l0 = pstats[NROWS + row];
  const float m1 = pstats[2 * NROWS + row], l1 = pstats[3 * NROWS + row];
  const float M = fmaxf(m0, m1);
  const float s0 = __expf(m0 - M), s1 = __expf(m1 - M);
  const float linv = 1.0f / (l0 * s0 + l1 * s1);
  float4 v0 = *(const float4*)(pacc + (long long)row * FOUT + col);
  float4 v1 = *(const float4*)(pacc + (long long)NROWS * FOUT + (long long)row * FOUT + col);
  float4 b = *(const float4*)(bias + col);
  float4 r;
  r.x = (v0.x * s0 + v1.x * s1) * linv + b.x;
  r.y = (v0.y * s0 + v1.y * s1) * linv + b.y;
  r.z = (v0.z * s0 + v1.z * s1) * linv + b.z;
  r.w = (v0.w * s0 + v1.w * s1) * linv + b.w;
  r.x = r.x > 0.f ? r.x : (__expf(r.x) - 1.f);
  r.y = r.y > 0.f ? r.y : (__expf(r.y) - 1.f);
  r.z = r.z > 0.f ? r.z : (__expf(r.z) - 1.f);
  r.w = r.w > 0.f ? r.w : (__expf(r.w) - 1.f);
  *(float4*)(out + (long long)row * FOUT + col) = r;
}

// ---------------- rwr: ri from per-row count of adj_ad in {2,3} --------------
__global__ void k_rwr(const int* __restrict__ adj_ad, float* __restrict__ out) {
  __shared__ int ssum[4];
  const int tid = threadIdx.x, row = blockIdx.x;
  const long long base = (long long)row * NROWS;
  int cnt = 0;
#pragma unroll
  for (int k = 0; k < 8; ++k) {
    int4 v = *(const int4*)(adj_ad + base + ((long long)(k * 256 + tid)) * 4);
    cnt += (v.x > 1 && v.x < 4) + (v.y > 1 && v.y < 4) + (v.z > 1 && v.z < 4) + (v.w > 1 && v.w < 4);
  }
#pragma unroll
  for (int mws = 1; mws < 64; mws <<= 1) cnt += __shfl_xor(cnt, mws, 64);
  if ((tid & 63) == 0) ssum[tid >> 6] = cnt;
  __syncthreads();
  if (tid == 0) {
    float kk = (float)(ssum[0] + ssum[1] + ssum[2] + ssum[3]);
    float denom = 1.0f - 0.25f * kk;
    float r0, rn;
    if (denom == 0.0f) { r0 = 1.0f; rn = 0.5f; }
    else { r0 = fabsf(1.0f / denom); rn = fabsf(0.5f / denom); }
    out[(long long)NROWS * FOUT + row * 2] = r0;
    out[(long long)NROWS * FOUT + row * 2 + 1] = rn;
  }
}

extern "C" void kernel_launch(void* const* d_in, const int* in_sizes, int n_in,
                              void* d_out, int out_size, void* d_ws, size_t ws_size,
                              hipStream_t stream) {
  const float* x = (const float*)d_in[0];
  const float* adj = (const float*)d_in[1];
  const int* adj_ad = (const int*)d_in[2];
  const float* seqW = (const float*)d_in[3];
  const float* f1w = (const float*)d_in[4];
  const float* f1b = (const float*)d_in[5];
  const float* f2w = (const float*)d_in[6];
  const float* f2b = (const float*)d_in[7];
  const float* bias = (const float*)d_in[8];
  float* out = (float*)d_out;

  char* ws = (char*)d_ws;
  unsigned short* ah = (unsigned short*)ws;                  // (N+FOUT)*FIN bf16 hi
  unsigned short* al = (unsigned short*)(ws + 17825792LL);   // lo residual
  float* sf = (float*)(ws + 35651584LL);                     // seq_fts fp32 [N][FOUT]
  unsigned short* vtp = (unsigned short*)(ws + 52428800LL);  // packed V frags, 8 MB
  float* f1 = (float*)(ws + 60817408LL);
  float* f2 = (float*)(ws + 60850176LL);                     // total 60,882,944 B
  // flash partials overlay ah/al (dead after k_gemm1):
  float* pacc = (float*)ws;                                  // 2 x N x FOUT fp32 = 32 MB
  float* pstats = (float*)(ws + 33554432LL);                 // 2 x (m[N], l[N]) = 128 KB

  hipLaunchKernelGGL(k_split, dim3(8704), dim3(256), 0, stream, x, seqW, ah, al);
  hipLaunchKernelGGL(k_gemm1, dim3(512), dim3(256), 0, stream, ah, al, sf);
  hipLaunchKernelGGL(k_f1f2, dim3(2048), dim3(256), 0, stream, sf, f1w, f1b, f2w, f2b, f1, f2);
  hipLaunchKernelGGL(k_pack, dim3(256, 16), dim3(256), 0, stream, sf, vtp);
  hipLaunchKernelGGL(k_flashp, dim3(512), dim3(512), 0, stream, adj, f1, f2, vtp, pacc, pstats);
  hipLaunchKernelGGL(k_combine, dim3(2048), dim3(512), 0, stream, pacc, pstats, bias, out);
  hipLaunchKernelGGL(k_rwr, dim3(8192), dim3(256), 0, stream, adj_ad, out);
}

// Round 2
// 668.597 us; speedup vs baseline: 1.1562x; 1.1562x over previous
//
#include <hip/hip_runtime.h>

#define NROWS 8192
#define FIN 1024
#define FOUT 512

typedef __attribute__((ext_vector_type(8))) short short8;
typedef __attribute__((ext_vector_type(4))) float f32x4;
typedef __attribute__((ext_vector_type(4))) unsigned short us4;

static __device__ __forceinline__ unsigned short f2bf(float f) {
  unsigned int u = __float_as_uint(f);
  u += 0x7fffu + ((u >> 16) & 1u);
  return (unsigned short)(u >> 16);
}
static __device__ __forceinline__ float bf2f(unsigned short h) {
  return __uint_as_float(((unsigned int)h) << 16);
}
static __device__ __forceinline__ void load_lds16(const void* g, void* l) {
  __builtin_amdgcn_global_load_lds((const __attribute__((address_space(1))) void*)g,
                                   (__attribute__((address_space(3))) void*)l, 16, 0, 0);
}

// 16-lane (DPP row) reductions -- pure VALU, no DS ops, ~4cy/step vs ~120cy
// for ds_swizzle-based __shfl_xor. Row groups (lanes sharing l>>4) align
// exactly with DPP's 16-lane rows. quad_perm xor1/xor2 reduce quads; row_ror
// 4/8 combine the four quad results (rotation works for commutative reduce).
static __device__ __forceinline__ float dpp16_max(float x) {
  int t;
  t = __builtin_amdgcn_update_dpp(0, __float_as_int(x), 0xB1, 0xf, 0xf, true);   // quad_perm [1,0,3,2]
  x = fmaxf(x, __int_as_float(t));
  t = __builtin_amdgcn_update_dpp(0, __float_as_int(x), 0x4E, 0xf, 0xf, true);   // quad_perm [2,3,0,1]
  x = fmaxf(x, __int_as_float(t));
  t = __builtin_amdgcn_update_dpp(0, __float_as_int(x), 0x124, 0xf, 0xf, true);  // row_ror:4
  x = fmaxf(x, __int_as_float(t));
  t = __builtin_amdgcn_update_dpp(0, __float_as_int(x), 0x128, 0xf, 0xf, true);  // row_ror:8
  x = fmaxf(x, __int_as_float(t));
  return x;
}
static __device__ __forceinline__ float dpp16_add(float x) {
  int t;
  t = __builtin_amdgcn_update_dpp(0, __float_as_int(x), 0xB1, 0xf, 0xf, true);
  x += __int_as_float(t);
  t = __builtin_amdgcn_update_dpp(0, __float_as_int(x), 0x4E, 0xf, 0xf, true);
  x += __int_as_float(t);
  t = __builtin_amdgcn_update_dpp(0, __float_as_int(x), 0x124, 0xf, 0xf, true);
  x += __int_as_float(t);
  t = __builtin_amdgcn_update_dpp(0, __float_as_int(x), 0x128, 0xf, 0xf, true);
  x += __int_as_float(t);
  return x;
}

// ---------------- split-cast: fp32 -> (bf16 hi, bf16 lo residual) -------------
__global__ void k_split(const float* __restrict__ x, const float* __restrict__ w,
                        unsigned short* __restrict__ hi, unsigned short* __restrict__ lo) {
  long long base = ((long long)blockIdx.x * blockDim.x + threadIdx.x) * 4;
  const long long NX = (long long)NROWS * FIN;
  const float* src = (base < NX) ? (x + base) : (w + (base - NX));
  float4 v = *(const float4*)src;
  unsigned short h0 = f2bf(v.x), h1 = f2bf(v.y), h2 = f2bf(v.z), h3 = f2bf(v.w);
  us4 hv = {h0, h1, h2, h3};
  us4 lv = {f2bf(v.x - bf2f(h0)), f2bf(v.y - bf2f(h1)),
            f2bf(v.z - bf2f(h2)), f2bf(v.w - bf2f(h3))};
  *(us4*)(hi + base) = hv;
  *(us4*)(lo + base) = lv;
}

// ---------------- GEMM1: seq_fts = x @ seq_W^T, split-bf16 (3 MFMA terms) -----
__global__ __launch_bounds__(256) void k_gemm1(const unsigned short* __restrict__ ah,
                                               const unsigned short* __restrict__ al,
                                               float* __restrict__ c) {
  __shared__ unsigned short sAh[128 * 32], sAl[128 * 32], sBh[64 * 32], sBl[64 * 32];
  const int tid = threadIdx.x;
  const int w = tid >> 6, l = tid & 63;
  const int bm = blockIdx.x >> 3, bn = blockIdx.x & 7;
  const int i0 = bm * 128, n0 = bn * 64;
  const unsigned short* bhp = ah + (long long)NROWS * FIN;
  const unsigned short* blp = al + (long long)NROWS * FIN;
  const int m_off = (w & 1) * 64, n_off = (w >> 1) * 32;
  const int lrow = l >> 2, lch = (l & 3) * 8;
  f32x4 acc[4][2] = {};
  for (int k0 = 0; k0 < FIN; k0 += 32) {
    __syncthreads();
    {
      int rA0 = w * 32, rA1 = w * 32 + 16, rB = w * 16;
      long long ga0 = (long long)(i0 + rA0 + lrow) * FIN + k0 + lch;
      long long ga1 = (long long)(i0 + rA1 + lrow) * FIN + k0 + lch;
      long long gb = (long long)(n0 + rB + lrow) * FIN + k0 + lch;
      load_lds16(ah + ga0, &sAh[rA0 * 32]);
      load_lds16(ah + ga1, &sAh[rA1 * 32]);
      load_lds16(al + ga0, &sAl[rA0 * 32]);
      load_lds16(al + ga1, &sAl[rA1 * 32]);
      load_lds16(bhp + gb, &sBh[rB * 32]);
      load_lds16(blp + gb, &sBl[rB * 32]);
    }
    __syncthreads();
    short8 a_h[4], a_l[4], b_h[2], b_l[2];
#pragma unroll
    for (int mi = 0; mi < 4; ++mi) {
      int off = (m_off + mi * 16 + (l & 15)) * 32 + (l >> 4) * 8;
      a_h[mi] = *(const short8*)&sAh[off];
      a_l[mi] = *(const short8*)&sAl[off];
    }
#pragma unroll
    for (int ni = 0; ni < 2; ++ni) {
      int off = (n_off + ni * 16 + (l & 15)) * 32 + (l >> 4) * 8;
      b_h[ni] = *(const short8*)&sBh[off];
      b_l[ni] = *(const short8*)&sBl[off];
    }
#pragma unroll
    for (int mi = 0; mi < 4; ++mi)
#pragma unroll
      for (int ni = 0; ni < 2; ++ni) {
        acc[mi][ni] = __builtin_amdgcn_mfma_f32_16x16x32_bf16(a_h[mi], b_h[ni], acc[mi][ni], 0, 0, 0);
        acc[mi][ni] = __builtin_amdgcn_mfma_f32_16x16x32_bf16(a_h[mi], b_l[ni], acc[mi][ni], 0, 0, 0);
        acc[mi][ni] = __builtin_amdgcn_mfma_f32_16x16x32_bf16(a_l[mi], b_h[ni], acc[mi][ni], 0, 0, 0);
      }
  }
#pragma unroll
  for (int mi = 0; mi < 4; ++mi)
#pragma unroll
    for (int ni = 0; ni < 2; ++ni)
#pragma unroll
      for (int rg = 0; rg < 4; ++rg) {
        int row = i0 + m_off + mi * 16 + (l >> 4) * 4 + rg;
        int col = n0 + n_off + ni * 16 + (l & 15);
        c[(long long)row * FOUT + col] = acc[mi][ni][rg];
      }
}

// ---------------- f1/f2: per-row dots of seq_fts with f1_w / f2_w ------------
__global__ void k_f1f2(const float* __restrict__ sf, const float* __restrict__ f1w,
                       const float* __restrict__ f1b, const float* __restrict__ f2w,
                       const float* __restrict__ f2b, float* __restrict__ f1,
                       float* __restrict__ f2) {
  int w = threadIdx.x >> 6, l = threadIdx.x & 63;
  int i = blockIdx.x * 4 + w;
  const float* row = sf + (long long)i * FOUT;
  float4 v0 = *(const float4*)(row + l * 8);
  float4 v1 = *(const float4*)(row + l * 8 + 4);
  float4 a0 = *(const float4*)(f1w + l * 8);
  float4 a1 = *(const float4*)(f1w + l * 8 + 4);
  float4 b0 = *(const float4*)(f2w + l * 8);
  float4 b1 = *(const float4*)(f2w + l * 8 + 4);
  float s1 = v0.x * a0.x + v0.y * a0.y + v0.z * a0.z + v0.w * a0.w +
             v1.x * a1.x + v1.y * a1.y + v1.z * a1.z + v1.w * a1.w;
  float s2 = v0.x * b0.x + v0.y * b0.y + v0.z * b0.z + v0.w * b0.w +
             v1.x * b1.x + v1.y * b1.y + v1.z * b1.z + v1.w * b1.w;
#pragma unroll
  for (int m = 1; m < 64; m <<= 1) {
    s1 += __shfl_xor(s1, m, 64);
    s2 += __shfl_xor(s2, m, 64);
  }
  if (l == 0) {
    f1[i] = s1 + f1b[0];
    f2[i] = s2 + f2b[0];
  }
}

// ---------------- pack: V into MFMA-B-fragment order ------------------------
// vtp[((kt*32 + nt)*64 + lane)*8 + j] = bf16(sf[kt*32 + (lane>>4)*8 + j][nt*16 + (lane&15)])
__global__ __launch_bounds__(256) void k_pack(const float* __restrict__ sf,
                                              unsigned short* __restrict__ vtp) {
  __shared__ unsigned short tile[32][33];
  const int t = threadIdx.x;
  const int k0 = blockIdx.x * 32;   // NROWS/32 = 256
  const int n0 = blockIdx.y * 32;   // FOUT/32 = 16
  {
    int kk = t >> 3, nq = (t & 7) * 4;
    float4 v = *(const float4*)(sf + (long long)(k0 + kk) * FOUT + n0 + nq);
    tile[kk][nq] = f2bf(v.x);
    tile[kk][nq + 1] = f2bf(v.y);
    tile[kk][nq + 2] = f2bf(v.z);
    tile[kk][nq + 3] = f2bf(v.w);
  }
  __syncthreads();
  int nt_loc = t >> 7, tt = t & 127;
  int lane = tt >> 1, jh = (tt & 1) * 4;
  int n_loc = nt_loc * 16 + (lane & 15);
  int k_loc = (lane >> 4) * 8 + jh;
  us4 u = {tile[k_loc][n_loc], tile[k_loc + 1][n_loc], tile[k_loc + 2][n_loc],
           tile[k_loc + 3][n_loc]};
  long long kt = blockIdx.x;
  long long nt = (long long)blockIdx.y * 2 + nt_loc;
  *(us4*)(vtp + ((kt * 32 + nt) * 64 + lane) * 8 + jh) = u;
}

// ---------------- flash attention partials (split-j 2-way) -------------------
// 512 blocks x 512 threads; 32 Q-rows/block; each block covers 4096 j-cols.
// v2: (a) DPP-based 16-lane reduces (no DS shuffles on the critical path),
//     (b) vtp B-fragments prefetched into registers at tile top -- their
//         L2/L3 latency hides under the softmax phase instead of stalling
//         the post-barrier MFMA phase.
__global__ __launch_bounds__(512) void k_flashp(const float* __restrict__ adj,
                                                const float* __restrict__ f1,
                                                const float* __restrict__ f2,
                                                const unsigned short* __restrict__ vtp,
                                                float* __restrict__ pacc,
                                                float* __restrict__ pstats) {
  __shared__ short p_sh[2][2][4][64][8];  // [buf][mi][ks][lane][8] = 16 KB
  __shared__ float alpha_sh[2][32];
  const int tid = threadIdx.x, l = tid & 63, w = tid >> 6;
  const int rloc = tid >> 4, c16 = tid & 15;
  // blockIdx -> (part, rb): bit2 selects partition (XCD round-robin mod 8)
  const int part = (blockIdx.x >> 2) & 1;
  const int rb = ((blockIdx.x >> 3) << 2) | (blockIdx.x & 3);
  const int r0 = rb * 32;
  const int jbase = part * 4096;
  const long long arow = (long long)(r0 + rloc) * NROWS;
  const float f1r = f1[r0 + rloc];
  const int nt_base = w * 4;  // 4 n-tiles of 16 per wave -> 64 cols
  const int mi_p = rloc >> 4;
  const int ks_p = c16 >> 2;
  const int lp = (rloc & 15) | ((c16 & 3) << 4);
  float m = -3.0e38f, lsum = 0.f;
  f32x4 acc[2][4] = {};
  float4 a0 = *(const float4*)(adj + arow + jbase + c16 * 8);
  float4 a1 = *(const float4*)(adj + arow + jbase + c16 * 8 + 4);
  float4 f20 = *(const float4*)(f2 + jbase + c16 * 8);
  float4 f21 = *(const float4*)(f2 + jbase + c16 * 8 + 4);
  for (int t = 0; t < 32; ++t) {
    const int j0 = jbase + t * 128;
    const int buf = t & 1;
    // ---- issue this tile's vtp loads now; softmax hides their latency ----
    short8 vb[4][4];
    {
      const unsigned short* bb =
          vtp + (((long long)(j0 >> 5) * 32 + nt_base) * 64 + l) * 8;
#pragma unroll
      for (int ks = 0; ks < 4; ++ks)
#pragma unroll
        for (int ni = 0; ni < 4; ++ni)
          vb[ks][ni] = *(const short8*)(bb + ks * 16384 + ni * 512);
    }
    float z, p0, p1, p2, p3, p4, p5, p6, p7;
    z = f1r + f20.x; p0 = (z > 0.f ? z : 0.2f * z) + a0.x;
    z = f1r + f20.y; p1 = (z > 0.f ? z : 0.2f * z) + a0.y;
    z = f1r + f20.z; p2 = (z > 0.f ? z : 0.2f * z) + a0.z;
    z = f1r + f20.w; p3 = (z > 0.f ? z : 0.2f * z) + a0.w;
    z = f1r + f21.x; p4 = (z > 0.f ? z : 0.2f * z) + a1.x;
    z = f1r + f21.y; p5 = (z > 0.f ? z : 0.2f * z) + a1.y;
    z = f1r + f21.z; p6 = (z > 0.f ? z : 0.2f * z) + a1.z;
    z = f1r + f21.w; p7 = (z > 0.f ? z : 0.2f * z) + a1.w;
    float mt = fmaxf(fmaxf(fmaxf(p0, p1), fmaxf(p2, p3)), fmaxf(fmaxf(p4, p5), fmaxf(p6, p7)));
    mt = dpp16_max(mt);  // row-of-16 max, pure VALU
    float m_new = fmaxf(m, mt);
    float al = __expf(m - m_new);  // == 1.0 when max unchanged
    p0 = __expf(p0 - m_new); p1 = __expf(p1 - m_new);
    p2 = __expf(p2 - m_new); p3 = __expf(p3 - m_new);
    p4 = __expf(p4 - m_new); p5 = __expf(p5 - m_new);
    p6 = __expf(p6 - m_new); p7 = __expf(p7 - m_new);
    float ps = p0 + p1 + p2 + p3 + p4 + p5 + p6 + p7;
    ps = dpp16_add(ps);  // row-of-16 sum, pure VALU
    lsum = lsum * al + ps;
    m = m_new;
    if (c16 == 0) alpha_sh[buf][rloc] = al;
    short8 pv;
    pv[0] = (short)f2bf(p0); pv[1] = (short)f2bf(p1);
    pv[2] = (short)f2bf(p2); pv[3] = (short)f2bf(p3);
    pv[4] = (short)f2bf(p4); pv[5] = (short)f2bf(p5);
    pv[6] = (short)f2bf(p6); pv[7] = (short)f2bf(p7);
    *(short8*)&p_sh[buf][mi_p][ks_p][lp][0] = pv;
    // prefetch next tile's adj/f2 -- these stay in flight across the barrier
    const int jn = (t < 31) ? j0 + 128 : j0;
    float4 na0 = *(const float4*)(adj + arow + jn + c16 * 8);
    float4 na1 = *(const float4*)(adj + arow + jn + c16 * 8 + 4);
    float4 nf20 = *(const float4*)(f2 + jn + c16 * 8);
    float4 nf21 = *(const float4*)(f2 + jn + c16 * 8 + 4);
    // barrier with LDS-only drain: VMEM prefetches NOT drained
    asm volatile("s_waitcnt lgkmcnt(0)" ::: "memory");
    __builtin_amdgcn_s_barrier();
    asm volatile("" ::: "memory");
    // always-rescale (alpha broadcast-read from LDS; same-address = free)
    {
      f32x4 al0 = *(const f32x4*)&alpha_sh[buf][(l >> 4) * 4];
      f32x4 al1 = *(const f32x4*)&alpha_sh[buf][16 + (l >> 4) * 4];
#pragma unroll
      for (int ni = 0; ni < 4; ++ni)
#pragma unroll
        for (int rg = 0; rg < 4; ++rg) {
          acc[0][ni][rg] *= al0[rg];
          acc[1][ni][rg] *= al1[rg];
        }
    }
    __builtin_amdgcn_s_setprio(1);
#pragma unroll
    for (int ks = 0; ks < 4; ++ks) {
      short8 af0 = *(const short8*)&p_sh[buf][0][ks][l][0];
      short8 af1 = *(const short8*)&p_sh[buf][1][ks][l][0];
#pragma unroll
      for (int ni = 0; ni < 4; ++ni) {
        acc[0][ni] = __builtin_amdgcn_mfma_f32_16x16x32_bf16(af0, vb[ks][ni], acc[0][ni], 0, 0, 0);
        acc[1][ni] = __builtin_amdgcn_mfma_f32_16x16x32_bf16(af1, vb[ks][ni], acc[1][ni], 0, 0, 0);
      }
    }
    __builtin_amdgcn_s_setprio(0);
    a0 = na0; a1 = na1; f20 = nf20; f21 = nf21;
  }
  // per-row stats (m, lsum replicated across the 16 lanes of a row group)
  if (c16 == 0) {
    pstats[part * 2 * NROWS + (r0 + rloc)] = m;
    pstats[part * 2 * NROWS + NROWS + (r0 + rloc)] = lsum;
  }
  // unnormalized partial accumulator
  float* pc = pacc + (long long)part * NROWS * FOUT;
#pragma unroll
  for (int mi = 0; mi < 2; ++mi)
#pragma unroll
    for (int rg = 0; rg < 4; ++rg) {
      int row = mi * 16 + (l >> 4) * 4 + rg;
      long long gr = (long long)(r0 + row) * FOUT;
#pragma unroll
      for (int ni = 0; ni < 4; ++ni) {
        int col = w * 64 + ni * 16 + (l & 15);
        pc[gr + col] = acc[mi][ni][rg];
      }
    }
}

// ---------------- combine the two j-partitions + bias + elu ------------------
__global__ __launch_bounds__(512) void k_combine(const float* __restrict__ pacc,
                                                 const float* __restrict__ pstats,
                                                 const float* __restrict__ bias,
                                                 float* __restrict__ out) {
  const int tid = threadIdx.x;
  const int row = blockIdx.x * 4 + (tid >> 7);
  const int col = (tid & 127) * 4;
  const float m0 = pstats[row], l0 = pstats[NROWS + row];
  const float m1 = pstats[2 * NROWS + row], l1 = pstats[3 * NROWS + row];
  const float M = fmaxf(m0, m1);
  const float s0 = __expf(m0 - M), s1 = __expf(m1 - M);
  const float linv = 1.0f / (l0 * s0 + l1 * s1);
  float4 v0 = *(const float4*)(pacc + (long long)row * FOUT + col);
  float4 v1 = *(const float4*)(pacc + (long long)NROWS * FOUT + (long long)row * FOUT + col);
  float4 b = *(const float4*)(bias + col);
  float4 r;
  r.x = (v0.x * s0 + v1.x * s1) * linv + b.x;
  r.y = (v0.y * s0 + v1.y * s1) * linv + b.y;
  r.z = (v0.z * s0 + v1.z * s1) * linv + b.z;
  r.w = (v0.w * s0 + v1.w * s1) * linv + b.w;
  r.x = r.x > 0.f ? r.x : (__expf(r.x) - 1.f);
  r.y = r.y > 0.f ? r.y : (__expf(r.y) - 1.f);
  r.z = r.z > 0.f ? r.z : (__expf(r.z) - 1.f);
  r.w = r.w > 0.f ? r.w : (__expf(r.w) - 1.f);
  *(float4*)(out + (long long)row * FOUT + col) = r;
}

// ---------------- rwr: ri from per-row count of adj_ad in {2,3} --------------
__global__ void k_rwr(const int* __restrict__ adj_ad, float* __restrict__ out) {
  __shared__ int ssum[4];
  const int tid = threadIdx.x, row = blockIdx.x;
  const long long base = (long long)row * NROWS;
  int cnt = 0;
#pragma unroll
  for (int k = 0; k < 8; ++k) {
    int4 v = *(const int4*)(adj_ad + base + ((long long)(k * 256 + tid)) * 4);
    cnt += (v.x > 1 && v.x < 4) + (v.y > 1 && v.y < 4) + (v.z > 1 && v.z < 4) + (v.w > 1 && v.w < 4);
  }
#pragma unroll
  for (int mws = 1; mws < 64; mws <<= 1) cnt += __shfl_xor(cnt, mws, 64);
  if ((tid & 63) == 0) ssum[tid >> 6] = cnt;
  __syncthreads();
  if (tid == 0) {
    float kk = (float)(ssum[0] + ssum[1] + ssum[2] + ssum[3]);
    float denom = 1.0f - 0.25f * kk;
    float r0, rn;
    if (denom == 0.0f) { r0 = 1.0f; rn = 0.5f; }
    else { r0 = fabsf(1.0f / denom); rn = fabsf(0.5f / denom); }
    out[(long long)NROWS * FOUT + row * 2] = r0;
    out[(long long)NROWS * FOUT + row * 2 + 1] = rn;
  }
}

extern "C" void kernel_launch(void* const* d_in, const int* in_sizes, int n_in,
                              void* d_out, int out_size, void* d_ws, size_t ws_size,
                              hipStream_t stream) {
  const float* x = (const float*)d_in[0];
  const float* adj = (const float*)d_in[1];
  const int* adj_ad = (const int*)d_in[2];
  const float* seqW = (const float*)d_in[3];
  const float* f1w = (const float*)d_in[4];
  const float* f1b = (const float*)d_in[5];
  const float* f2w = (const float*)d_in[6];
  const float* f2b = (const float*)d_in[7];
  const float* bias = (const float*)d_in[8];
  float* out = (float*)d_out;

  char* ws = (char*)d_ws;
  unsigned short* ah = (unsigned short*)ws;                  // (N+FOUT)*FIN bf16 hi
  unsigned short* al = (unsigned short*)(ws + 17825792LL);   // lo residual
  float* sf = (float*)(ws + 35651584LL);                     // seq_fts fp32 [N][FOUT]
  unsigned short* vtp = (unsigned short*)(ws + 52428800LL);  // packed V frags, 8 MB
  float* f1 = (float*)(ws + 60817408LL);
  float* f2 = (float*)(ws + 60850176LL);                     // total 60,882,944 B
  // flash partials overlay ah/al (dead after k_gemm1):
  float* pacc = (float*)ws;                                  // 2 x N x FOUT fp32 = 32 MB
  float* pstats = (float*)(ws + 33554432LL);                 // 2 x (m[N], l[N]) = 128 KB

  hipLaunchKernelGGL(k_split, dim3(8704), dim3(256), 0, stream, x, seqW, ah, al);
  hipLaunchKernelGGL(k_gemm1, dim3(512), dim3(256), 0, stream, ah, al, sf);
  hipLaunchKernelGGL(k_f1f2, dim3(2048), dim3(256), 0, stream, sf, f1w, f1b, f2w, f2b, f1, f2);
  hipLaunchKernelGGL(k_pack, dim3(256, 16), dim3(256), 0, stream, sf, vtp);
  hipLaunchKernelGGL(k_flashp, dim3(512), dim3(512), 0, stream, adj, f1, f2, vtp, pacc, pstats);
  hipLaunchKernelGGL(k_combine, dim3(2048), dim3(512), 0, stream, pacc, pstats, bias, out);
  hipLaunchKernelGGL(k_rwr, dim3(8192), dim3(256), 0, stream, adj_ad, out);
}